// Round 7
// baseline (679.578 us; speedup 1.0000x reference)
//
#include <hip/hip_runtime.h>
#include <hip/hip_bf16.h>
#include <cstdint>
#include <cstddef>

// MHA: B=4, S=2048, D=512, H=8, DH=64. fp32 in/out.
// R7: flash = R5 structure (key-split waves, K/V LDS-staged, permuted-V PV
//     trick) but K_lo loaded direct global->VGPR so LDS drops 49->33 KB ->
//     4 blocks/CU and grid 1024 fits in ONE round (no tail).
//     __launch_bounds__(256,4) to pin VGPR<=128. Two-phase epilogue reduce.

typedef __bf16 bf16;
typedef __attribute__((ext_vector_type(8))) __bf16 bf16x8;
typedef __attribute__((ext_vector_type(4))) __bf16 bf16x4;
typedef __attribute__((ext_vector_type(4))) float floatx4;

#define MFMA16(a, b, c) __builtin_amdgcn_mfma_f32_16x16x32_bf16(a, b, c, 0, 0, 0)

#define GLD16(gp, lp)                                              \
  __builtin_amdgcn_global_load_lds(                                \
      (const __attribute__((address_space(1))) unsigned int*)(gp), \
      (__attribute__((address_space(3))) unsigned int*)(lp), 16, 0, 0)

__device__ __forceinline__ void split2(float x, bf16& hi, bf16& lo) {
  hi = (bf16)x;
  lo = (bf16)(x - (float)hi);
}

// ---------------------------------------------------------------------------
// Split + transpose the 4 weight matrices: wt[w][n][k] = W_w[k][n] as hi/lo bf16
// ---------------------------------------------------------------------------
__global__ __launch_bounds__(256) void k_split_w(
    const float* __restrict__ Wq, const float* __restrict__ Wk,
    const float* __restrict__ Wv, const float* __restrict__ Wo,
    bf16* __restrict__ wt_hi, bf16* __restrict__ wt_lo) {
  __shared__ float tile[64][65];
  const int w = blockIdx.z;
  const float* W = (w == 0) ? Wq : (w == 1) ? Wk : (w == 2) ? Wv : Wo;
  const int kb = blockIdx.y * 64, nb = blockIdx.x * 64;
  const int tid = threadIdx.x;
  const int col = tid & 63, rbase = tid >> 6;
#pragma unroll
  for (int i = 0; i < 16; i++) {
    int row = rbase + i * 4;
    tile[row][col] = W[(size_t)(kb + row) * 512 + nb + col];
  }
  __syncthreads();
#pragma unroll
  for (int i = 0; i < 16; i++) {
    int nrow = rbase + i * 4;
    float v = tile[col][nrow];
    bf16 hi, lo;
    split2(v, hi, lo);
    size_t o = (size_t)w * 262144 + (size_t)(nb + nrow) * 512 + (kb + col);
    wt_hi[o] = hi;
    wt_lo[o] = lo;
  }
}

// ---------------------------------------------------------------------------
// QKV projection, 128x128 C-tile, BK=32, global_load_lds staging.
// grid 768 (1-D, XCD-swizzled), block 256.
// Q scaled 1/8, K scaled log2(e). V stored transposed with slot-permuted
// columns (key 16t+4q+r -> column 8q+4t+r within each 32-group) so the flash
// PV MFMA consumes S^T C-layout registers directly as A-operand.
// ---------------------------------------------------------------------------
__global__ __launch_bounds__(256) void k_proj_qkv(
    const float* __restrict__ Xq, const float* __restrict__ Xk,
    const float* __restrict__ Xv,
    const bf16* __restrict__ wt_hi, const bf16* __restrict__ wt_lo,
    bf16* __restrict__ Q_hi, bf16* __restrict__ Q_lo,
    bf16* __restrict__ K_hi, bf16* __restrict__ K_lo,
    bf16* __restrict__ Vt) {
  const int P = blockIdx.x;
  const int c_all = P >> 5, within = P & 31;
  const int n_idx = within >> 3, i8 = within & 7;
  const int which = c_all >> 3;
  const int g = ((c_all & 7) << 3) | i8;  // m-group 0..63
  const int m0 = g * 128, n0 = n_idx * 128;

  const float* X = (which == 0) ? Xq : (which == 1) ? Xk : Xv;
  const uint8_t* Bhb = (const uint8_t*)(wt_hi + (size_t)which * 262144);
  const uint8_t* Blb = (const uint8_t*)(wt_lo + (size_t)which * 262144);
  const uint8_t* Xb = (const uint8_t*)X;
  const int tid = threadIdx.x, wave = tid >> 6, lane = tid & 63;
  const int l15 = lane & 15, l4 = lane >> 4;
  const int Am0 = (wave & 1) * 64, Bn0 = (wave >> 1) * 64;

  __shared__ float sA[128 * 32];                 // 16 KB, XOR-swizzled 16B blocks
  __shared__ bf16 sBh[128 * 32], sBl[128 * 32];  // 8 KB each

  int aoff[4], adst[4];
#pragma unroll
  for (int p = 0; p < 4; p++) {
    int slot = p * 256 + tid;
    int row = slot >> 3, phys = slot & 7, lg = phys ^ (row & 7);
    aoff[p] = (m0 + row) * 2048 + lg * 16;
    adst[p] = slot * 16;
  }
  int boff[2], bdst[2];
#pragma unroll
  for (int p = 0; p < 2; p++) {
    int slot = p * 256 + tid;
    int row = slot >> 2, phys = slot & 3, lg = phys ^ (row & 3);
    boff[p] = (n0 + row) * 1024 + lg * 16;
    bdst[p] = slot * 16;
  }

  floatx4 acc[4][4];
#pragma unroll
  for (int i = 0; i < 4; i++)
#pragma unroll
    for (int j = 0; j < 4; j++) acc[i][j] = {0.f, 0.f, 0.f, 0.f};

  for (int kb = 0; kb < 512; kb += 32) {
    __syncthreads();
#pragma unroll
    for (int p = 0; p < 4; p++) GLD16(Xb + aoff[p] + kb * 4, (char*)sA + adst[p]);
#pragma unroll
    for (int p = 0; p < 2; p++) {
      GLD16(Bhb + boff[p] + kb * 2, (char*)sBh + bdst[p]);
      GLD16(Blb + boff[p] + kb * 2, (char*)sBl + bdst[p]);
    }
    __syncthreads();

    bf16x8 ah[4], al[4];
#pragma unroll
    for (int mt = 0; mt < 4; mt++) {
      int row = Am0 + mt * 16 + l15, r7 = row & 7;
      const float* f0 = (const float*)((const char*)sA + row * 128 + (((2 * l4) ^ r7) * 16));
      const float* f1 = (const float*)((const char*)sA + row * 128 + (((2 * l4 + 1) ^ r7) * 16));
#pragma unroll
      for (int j = 0; j < 4; j++) {
        bf16 h, l;
        split2(f0[j], h, l);
        ah[mt][j] = h; al[mt][j] = l;
        split2(f1[j], h, l);
        ah[mt][4 + j] = h; al[mt][4 + j] = l;
      }
    }
#pragma unroll
    for (int nt = 0; nt < 4; nt++) {
      int row = Bn0 + nt * 16 + l15, r3 = row & 3;
      bf16x8 bh = *(const bf16x8*)((const char*)sBh + row * 64 + ((l4 ^ r3) * 16));
      bf16x8 bl = *(const bf16x8*)((const char*)sBl + row * 64 + ((l4 ^ r3) * 16));
#pragma unroll
      for (int mt = 0; mt < 4; mt++) {
        acc[mt][nt] = MFMA16(ah[mt], bh, acc[mt][nt]);
        acc[mt][nt] = MFMA16(ah[mt], bl, acc[mt][nt]);
        acc[mt][nt] = MFMA16(al[mt], bh, acc[mt][nt]);
      }
    }
  }

  const float scale = (which == 0) ? 0.125f : (which == 1) ? 1.44269504f : 1.0f;
#pragma unroll
  for (int mt = 0; mt < 4; mt++) {
#pragma unroll
    for (int nt = 0; nt < 4; nt++) {
      int m_base = m0 + Am0 + mt * 16 + l4 * 4;  // 4 consecutive rows (s)
      int n = n0 + Bn0 + nt * 16 + l15;          // h*64+d
      int h = (n >> 6) & 7, d = n & 63;
      if (which == 2) {
        // slot-permuted packed V^T store: keys 16t+4q+r -> column 8q+4t+r
        int kbase = m_base & 2047, b = m_base >> 11;
        int a32 = kbase & ~31, v = (kbase >> 2) & 7;
        int sbase = a32 + 8 * (v & 3) + 4 * (v >> 2);
        bf16x4 pv;
#pragma unroll
        for (int r = 0; r < 4; r++) pv[r] = (bf16)acc[mt][nt][r];
        *(bf16x4*)&Vt[((size_t)(b * 8 + h) * 64 + d) * 2048 + sbase] = pv;
      } else {
#pragma unroll
        for (int r = 0; r < 4; r++) {
          int m = m_base + r;
          int b = m >> 11, s = m & 2047;
          float v = acc[mt][nt][r] * scale;
          bf16 hi, lo;
          split2(v, hi, lo);
          size_t o = ((size_t)(b * 8 + h) * 2048 + s) * 64 + d;
          if (which == 0) { Q_hi[o] = hi; Q_lo[o] = lo; }
          else           { K_hi[o] = hi; K_lo[o] = lo; }
        }
      }
    }
  }
}

// ---------------------------------------------------------------------------
// Flash attention: grid 1024 (XCD-swizzled), block 256 = 4 waves, 4 blocks/CU.
// Block: 64 q x 128-key tile; wave w owns keys [32w,32w+32).
// K_hi, V staged via global_load_lds (LDS 33 KB); K_lo direct global->VGPR.
// S^T = K Q^T (3-term split); p = exp2(s - 24); PV consumes S^T C-layout
// directly as A-operand (V columns pre-permuted). Two-phase epilogue reduce.
// ---------------------------------------------------------------------------
__global__ __launch_bounds__(256, 4) void k_flash(
    const bf16* __restrict__ Q_hi, const bf16* __restrict__ Q_lo,
    const bf16* __restrict__ K_hi, const bf16* __restrict__ K_lo,
    const bf16* __restrict__ Vt,
    bf16* __restrict__ O_hi, bf16* __restrict__ O_lo) {
  const int P = blockIdx.x;
  const int hi4 = P >> 8, rem = P & 255;
  const int qt = rem >> 3;
  const int bh = hi4 * 8 + (rem & 7);
  const int b = bh >> 3, h = bh & 7;
  const int tid = threadIdx.x, wave = tid >> 6, lane = tid & 63;
  const int l15 = lane & 15, l4 = lane >> 4;
  const int q0 = qt * 64;

  __shared__ char smem[33792];  // sKh 16KB @0 | sV 16KB @16384 | lbuf 1KB @32768
  bf16* sKh = (bf16*)smem;
  bf16* sV = (bf16*)(smem + 16384);
  float* lbuf = (float*)(smem + 32768);

  // Q fragments (B operand): lane holds Q[q=l15][dh=l4*8+j]
  bf16x8 qh[4][2], ql[4][2];
#pragma unroll
  for (int nt = 0; nt < 4; nt++) {
    const bf16* ph = Q_hi + ((size_t)bh * 2048 + q0 + nt * 16 + l15) * 64 + l4 * 8;
    const bf16* pl = Q_lo + ((size_t)bh * 2048 + q0 + nt * 16 + l15) * 64 + l4 * 8;
    qh[nt][0] = *(const bf16x8*)ph;
    qh[nt][1] = *(const bf16x8*)(ph + 32);
    ql[nt][0] = *(const bf16x8*)pl;
    ql[nt][1] = *(const bf16x8*)(pl + 32);
  }

  const uint8_t* Khb = (const uint8_t*)K_hi + (size_t)bh * 2048 * 128;
  const uint8_t* Vb = (const uint8_t*)Vt + (size_t)bh * 64 * 4096;
  const bf16* Kl0 = K_lo + ((size_t)bh * 2048 + wave * 32 + l15) * 64 + l4 * 8;
  int koff[4], voff[4], dst[4];
#pragma unroll
  for (int p = 0; p < 4; p++) {
    int slot = p * 256 + tid;
    {
      int row = slot >> 3, phys = slot & 7, lg = phys ^ (row & 7);
      koff[p] = row * 128 + lg * 16;
    }
    {
      int row = slot >> 4, phys = slot & 15, lg = phys ^ (row & 15);
      voff[p] = row * 4096 + lg * 16;
    }
    dst[p] = slot * 16;
  }

  float lp[4] = {0.f, 0.f, 0.f, 0.f};  // l partial per q-tile (q = nt*16+l15)
  floatx4 oacc[4][4];
#pragma unroll
  for (int i = 0; i < 4; i++)
#pragma unroll
    for (int j = 0; j < 4; j++) oacc[i][j] = {0.f, 0.f, 0.f, 0.f};

  for (int j0 = 0; j0 < 2048; j0 += 128) {
    __syncthreads();
#pragma unroll
    for (int p = 0; p < 4; p++) {
      GLD16(Khb + (size_t)j0 * 128 + koff[p], (char*)sKh + dst[p]);
      GLD16(Vb + (size_t)j0 * 2 + voff[p], (char*)sV + dst[p]);
    }
    // K_lo fragments direct global->VGPR (L2-resident; covered by kh MFMAs)
    bf16x8 kl[2][2];
#pragma unroll
    for (int kt = 0; kt < 2; kt++)
#pragma unroll
      for (int ks = 0; ks < 2; ks++)
        kl[kt][ks] = *(const bf16x8*)(Kl0 + (size_t)(j0 + kt * 16) * 64 + ks * 32);
    __syncthreads();

    // S^T = K Q^T - 24: sc[kt][nt] C-tile: row=key(16), col=q (l15)
    floatx4 sc[2][4];
#pragma unroll
    for (int kt = 0; kt < 2; kt++)
#pragma unroll
      for (int nt = 0; nt < 4; nt++)
        sc[kt][nt] = {-24.f, -24.f, -24.f, -24.f};
#pragma unroll
    for (int kt = 0; kt < 2; kt++) {
      int row = wave * 32 + kt * 16 + l15;
      int r7 = row & 7;
#pragma unroll
      for (int ks = 0; ks < 2; ks++) {
        bf16x8 kh = *(const bf16x8*)((const char*)sKh +
                                     (row * 128 + (((ks * 4 + l4) ^ r7) * 16)));
#pragma unroll
        for (int nt = 0; nt < 4; nt++) {
          sc[kt][nt] = MFMA16(kh, qh[nt][ks], sc[kt][nt]);
          sc[kt][nt] = MFMA16(kh, ql[nt][ks], sc[kt][nt]);
          sc[kt][nt] = MFMA16(kl[kt][ks], qh[nt][ks], sc[kt][nt]);
        }
      }
    }

    // p = exp2(s); pf[nt] directly the PV A-operand (slot = quad*8 + 4*kt + r)
    bf16x8 pf[4];
#pragma unroll
    for (int nt = 0; nt < 4; nt++) {
#pragma unroll
      for (int r = 0; r < 4; r++) {
        float p0 = __builtin_amdgcn_exp2f(sc[0][nt][r]);
        float p1 = __builtin_amdgcn_exp2f(sc[1][nt][r]);
        lp[nt] += p0 + p1;
        pf[nt][r] = (bf16)p0;
        pf[nt][4 + r] = (bf16)p1;
      }
    }

    // O += P V over this wave's 32 slots
#pragma unroll
    for (int nt = 0; nt < 4; nt++) {  // dh tile
      int row = nt * 16 + l15;
      bf16x8 bv = *(const bf16x8*)((const char*)sV +
                                   (row * 256 + (((wave * 4 + l4) ^ l15) * 16)));
#pragma unroll
      for (int mq = 0; mq < 4; mq++)
        oacc[mq][nt] = MFMA16(pf[mq], bv, oacc[mq][nt]);
    }
  }

  // ---- epilogue: l reduce + two-phase cross-wave O reduction (24KB alias) ----
#pragma unroll
  for (int nt = 0; nt < 4; nt++) {
    lp[nt] += __shfl_xor(lp[nt], 16, 64);
    lp[nt] += __shfl_xor(lp[nt], 32, 64);
  }
  __syncthreads();  // everyone done with sKh/sV
  if (l4 == 0) {
#pragma unroll
    for (int nt = 0; nt < 4; nt++) lbuf[wave * 64 + nt * 16 + l15] = lp[nt];
  }
  floatx4* red = (floatx4*)smem;  // 3 waves x 8 x 64 = 1536 floatx4 = 24KB
#pragma unroll
  for (int phase = 0; phase < 2; phase++) {
    if (wave >= 1) {
#pragma unroll
      for (int i = 0; i < 8; i++) {
        int mq = phase * 2 + (i >> 2);
        red[(wave - 1) * 512 + i * 64 + lane] = oacc[mq][i & 3];
      }
    }
    __syncthreads();
    if (wave == 0) {
#pragma unroll
      for (int i = 0; i < 8; i++) {
        int mq = phase * 2 + (i >> 2);
        oacc[mq][i & 3] += red[i * 64 + lane] + red[512 + i * 64 + lane] +
                           red[1024 + i * 64 + lane];
      }
    }
    __syncthreads();
  }
  if (wave == 0) {
    float lt[4];
#pragma unroll
    for (int nt = 0; nt < 4; nt++)
      lt[nt] = lbuf[nt * 16 + l15] + lbuf[64 + nt * 16 + l15] +
               lbuf[128 + nt * 16 + l15] + lbuf[192 + nt * 16 + l15];
    float rl[4][4];
#pragma unroll
    for (int mq = 0; mq < 4; mq++)
#pragma unroll
      for (int r = 0; r < 4; r++)
        rl[mq][r] = 1.0f / __shfl(lt[mq], (lane & 48) | (l4 * 4 + r), 64);
#pragma unroll
    for (int mq = 0; mq < 4; mq++) {
#pragma unroll
      for (int nt = 0; nt < 4; nt++) {
#pragma unroll
        for (int r = 0; r < 4; r++) {
          float v = oacc[mq][nt][r] * rl[mq][r];
          int gs = q0 + mq * 16 + l4 * 4 + r;
          int gd = h * 64 + nt * 16 + l15;
          size_t o = ((size_t)b * 2048 + gs) * 512 + gd;
          bf16 hi, lo;
          split2(v, hi, lo);
          O_hi[o] = hi;
          O_lo[o] = lo;
        }
      }
    }
  }
}

// ---------------------------------------------------------------------------
// Output projection, 128x128 tile, BK=32, global_load_lds. grid 256 (swizzled).
// ---------------------------------------------------------------------------
__global__ __launch_bounds__(256) void k_proj_out(
    const bf16* __restrict__ O_hi, const bf16* __restrict__ O_lo,
    const bf16* __restrict__ wt_hi, const bf16* __restrict__ wt_lo,
    float* __restrict__ out) {
  const int P = blockIdx.x;
  const int c = P >> 5, within = P & 31;
  const int n_idx = within >> 3, i8 = within & 7;
  const int g = (c << 3) | i8;
  const int m0 = g * 128, n0 = n_idx * 128;

  const uint8_t* Ahb = (const uint8_t*)O_hi;
  const uint8_t* Alb = (const uint8_t*)O_lo;
  const uint8_t* Bhb = (const uint8_t*)(wt_hi + (size_t)3 * 262144);
  const uint8_t* Blb = (const uint8_t*)(wt_lo + (size_t)3 * 262144);
  const int tid = threadIdx.x, wave = tid >> 6, lane = tid & 63;
  const int l15 = lane & 15, l4 = lane >> 4;
  const int Am0 = (wave & 1) * 64, Bn0 = (wave >> 1) * 64;

  __shared__ bf16 sAh[128 * 32], sAl[128 * 32];
  __shared__ bf16 sBh[128 * 32], sBl[128 * 32];

  int aoff[2], boff[2], dst[2];
#pragma unroll
  for (int p = 0; p < 2; p++) {
    int slot = p * 256 + tid;
    int row = slot >> 2, phys = slot & 3, lg = phys ^ (row & 3);
    aoff[p] = (m0 + row) * 1024 + lg * 16;
    boff[p] = (n0 + row) * 1024 + lg * 16;
    dst[p] = slot * 16;
  }

  floatx4 acc[4][4];
#pragma unroll
  for (int i = 0; i < 4; i++)
#pragma unroll
    for (int j = 0; j < 4; j++) acc[i][j] = {0.f, 0.f, 0.f, 0.f};

  for (int kb = 0; kb < 512; kb += 32) {
    __syncthreads();
#pragma unroll
    for (int p = 0; p < 2; p++) {
      GLD16(Ahb + aoff[p] + kb * 2, (char*)sAh + dst[p]);
      GLD16(Alb + aoff[p] + kb * 2, (char*)sAl + dst[p]);
      GLD16(Bhb + boff[p] + kb * 2, (char*)sBh + dst[p]);
      GLD16(Blb + boff[p] + kb * 2, (char*)sBl + dst[p]);
    }
    __syncthreads();

    bf16x8 ah[4], al[4];
#pragma unroll
    for (int mt = 0; mt < 4; mt++) {
      int row = Am0 + mt * 16 + l15, r3 = row & 3;
      ah[mt] = *(const bf16x8*)((const char*)sAh + row * 64 + ((l4 ^ r3) * 16));
      al[mt] = *(const bf16x8*)((const char*)sAl + row * 64 + ((l4 ^ r3) * 16));
    }
#pragma unroll
    for (int nt = 0; nt < 4; nt++) {
      int row = Bn0 + nt * 16 + l15, r3 = row & 3;
      bf16x8 bh = *(const bf16x8*)((const char*)sBh + row * 64 + ((l4 ^ r3) * 16));
      bf16x8 bl = *(const bf16x8*)((const char*)sBl + row * 64 + ((l4 ^ r3) * 16));
#pragma unroll
      for (int mt = 0; mt < 4; mt++) {
        acc[mt][nt] = MFMA16(ah[mt], bh, acc[mt][nt]);
        acc[mt][nt] = MFMA16(ah[mt], bl, acc[mt][nt]);
        acc[mt][nt] = MFMA16(al[mt], bh, acc[mt][nt]);
      }
    }
  }
#pragma unroll
  for (int mt = 0; mt < 4; mt++) {
#pragma unroll
    for (int nt = 0; nt < 4; nt++) {
#pragma unroll
      for (int r = 0; r < 4; r++) {
        int m = m0 + Am0 + mt * 16 + l4 * 4 + r;
        int n = n0 + Bn0 + nt * 16 + l15;
        out[(size_t)m * 512 + n] = acc[mt][nt][r];
      }
    }
  }
}

// ---------------------------------------------------------------------------
extern "C" void kernel_launch(void* const* d_in, const int* in_sizes, int n_in,
                              void* d_out, int out_size, void* d_ws, size_t ws_size,
                              hipStream_t stream) {
  (void)in_sizes; (void)n_in; (void)out_size; (void)ws_size;
  const float* Xq = (const float*)d_in[0];
  const float* Xk = (const float*)d_in[1];
  const float* Xv = (const float*)d_in[2];
  const float* Wq = (const float*)d_in[3];
  const float* Wk = (const float*)d_in[4];
  const float* Wv = (const float*)d_in[5];
  const float* Wo = (const float*)d_in[6];
  float* out = (float*)d_out;

  char* ws = (char*)d_ws;
  size_t off = 0;
  auto alloc = [&](size_t n) {
    void* p = ws + off;
    off += (n + 255) & ~(size_t)255;
    return p;
  };
  const size_t NW = 4 * 262144;
  const size_t NE = 4194304;  // 4*2048*512
  bf16* wt_hi = (bf16*)alloc(NW * 2);
  bf16* wt_lo = (bf16*)alloc(NW * 2);
  bf16* Qh = (bf16*)alloc(NE * 2);
  bf16* Ql = (bf16*)alloc(NE * 2);
  bf16* Kh = (bf16*)alloc(NE * 2);
  bf16* Kl = (bf16*)alloc(NE * 2);
  bf16* Vt = (bf16*)alloc(NE * 2);
  bf16* Oh = (bf16*)alloc(NE * 2);
  bf16* Ol = (bf16*)alloc(NE * 2);

  k_split_w<<<dim3(8, 8, 4), dim3(256), 0, stream>>>(Wq, Wk, Wv, Wo, wt_hi, wt_lo);
  k_proj_qkv<<<dim3(768), dim3(256), 0, stream>>>(Xq, Xk, Xv, wt_hi, wt_lo,
                                                  Qh, Ql, Kh, Kl, Vt);
  k_flash<<<dim3(1024), dim3(256), 0, stream>>>(Qh, Ql, Kh, Kl, Vt, Oh, Ol);
  k_proj_out<<<dim3(256), dim3(256), 0, stream>>>(Oh, Ol, wt_hi, wt_lo, out);
}

// Round 8
// 340.891 us; speedup vs baseline: 1.9935x; 1.9935x over previous
//
#include <hip/hip_runtime.h>
#include <hip/hip_bf16.h>
#include <cstdint>
#include <cstddef>

// MHA: B=4, S=2048, D=512, H=8, DH=64. fp32 in/out.
// R8: flash = R5/R7 key-split structure, but K is SINGLE bf16 (2-term QK:
//     kh*qh + kh*ql; K-rounding err ~1e-4 at output) -> LDS 33 KB, 32 MFMA/iter,
//     no K_lo anywhere. __launch_bounds__(256,3) (cap 170; R7's (256,4)=64 cap
//     caused 2.4 GB of scratch spills). Projections as R4 + single-K output.

typedef __bf16 bf16;
typedef __attribute__((ext_vector_type(8))) __bf16 bf16x8;
typedef __attribute__((ext_vector_type(4))) __bf16 bf16x4;
typedef __attribute__((ext_vector_type(4))) float floatx4;

#define MFMA16(a, b, c) __builtin_amdgcn_mfma_f32_16x16x32_bf16(a, b, c, 0, 0, 0)

#define GLD16(gp, lp)                                              \
  __builtin_amdgcn_global_load_lds(                                \
      (const __attribute__((address_space(1))) unsigned int*)(gp), \
      (__attribute__((address_space(3))) unsigned int*)(lp), 16, 0, 0)

__device__ __forceinline__ void split2(float x, bf16& hi, bf16& lo) {
  hi = (bf16)x;
  lo = (bf16)(x - (float)hi);
}

// ---------------------------------------------------------------------------
// Split + transpose the 4 weight matrices: wt[w][n][k] = W_w[k][n] as hi/lo bf16
// ---------------------------------------------------------------------------
__global__ __launch_bounds__(256) void k_split_w(
    const float* __restrict__ Wq, const float* __restrict__ Wk,
    const float* __restrict__ Wv, const float* __restrict__ Wo,
    bf16* __restrict__ wt_hi, bf16* __restrict__ wt_lo) {
  __shared__ float tile[64][65];
  const int w = blockIdx.z;
  const float* W = (w == 0) ? Wq : (w == 1) ? Wk : (w == 2) ? Wv : Wo;
  const int kb = blockIdx.y * 64, nb = blockIdx.x * 64;
  const int tid = threadIdx.x;
  const int col = tid & 63, rbase = tid >> 6;
#pragma unroll
  for (int i = 0; i < 16; i++) {
    int row = rbase + i * 4;
    tile[row][col] = W[(size_t)(kb + row) * 512 + nb + col];
  }
  __syncthreads();
#pragma unroll
  for (int i = 0; i < 16; i++) {
    int nrow = rbase + i * 4;
    float v = tile[col][nrow];
    bf16 hi, lo;
    split2(v, hi, lo);
    size_t o = (size_t)w * 262144 + (size_t)(nb + nrow) * 512 + (kb + col);
    wt_hi[o] = hi;
    wt_lo[o] = lo;
  }
}

// ---------------------------------------------------------------------------
// QKV projection, 128x128 C-tile, BK=32, global_load_lds staging.
// grid 768 (1-D, XCD-swizzled), block 256.
// Q split hi/lo, scaled 1/8. K SINGLE bf16, scaled log2(e). V single bf16,
// transposed with slot-permuted columns (key 16t+4q+r -> column 8q+4t+r per
// 32-group) so flash PV consumes S^T C-layout registers directly as A.
// ---------------------------------------------------------------------------
__global__ __launch_bounds__(256) void k_proj_qkv(
    const float* __restrict__ Xq, const float* __restrict__ Xk,
    const float* __restrict__ Xv,
    const bf16* __restrict__ wt_hi, const bf16* __restrict__ wt_lo,
    bf16* __restrict__ Q_hi, bf16* __restrict__ Q_lo,
    bf16* __restrict__ K, bf16* __restrict__ Vt) {
  const int P = blockIdx.x;
  const int c_all = P >> 5, within = P & 31;
  const int n_idx = within >> 3, i8 = within & 7;
  const int which = c_all >> 3;
  const int g = ((c_all & 7) << 3) | i8;  // m-group 0..63
  const int m0 = g * 128, n0 = n_idx * 128;

  const float* X = (which == 0) ? Xq : (which == 1) ? Xk : Xv;
  const uint8_t* Bhb = (const uint8_t*)(wt_hi + (size_t)which * 262144);
  const uint8_t* Blb = (const uint8_t*)(wt_lo + (size_t)which * 262144);
  const uint8_t* Xb = (const uint8_t*)X;
  const int tid = threadIdx.x, wave = tid >> 6, lane = tid & 63;
  const int l15 = lane & 15, l4 = lane >> 4;
  const int Am0 = (wave & 1) * 64, Bn0 = (wave >> 1) * 64;

  __shared__ float sA[128 * 32];                 // 16 KB, XOR-swizzled 16B blocks
  __shared__ bf16 sBh[128 * 32], sBl[128 * 32];  // 8 KB each

  int aoff[4], adst[4];
#pragma unroll
  for (int p = 0; p < 4; p++) {
    int slot = p * 256 + tid;
    int row = slot >> 3, phys = slot & 7, lg = phys ^ (row & 7);
    aoff[p] = (m0 + row) * 2048 + lg * 16;
    adst[p] = slot * 16;
  }
  int boff[2], bdst[2];
#pragma unroll
  for (int p = 0; p < 2; p++) {
    int slot = p * 256 + tid;
    int row = slot >> 2, phys = slot & 3, lg = phys ^ (row & 3);
    boff[p] = (n0 + row) * 1024 + lg * 16;
    bdst[p] = slot * 16;
  }

  floatx4 acc[4][4];
#pragma unroll
  for (int i = 0; i < 4; i++)
#pragma unroll
    for (int j = 0; j < 4; j++) acc[i][j] = {0.f, 0.f, 0.f, 0.f};

  for (int kb = 0; kb < 512; kb += 32) {
    __syncthreads();
#pragma unroll
    for (int p = 0; p < 4; p++) GLD16(Xb + aoff[p] + kb * 4, (char*)sA + adst[p]);
#pragma unroll
    for (int p = 0; p < 2; p++) {
      GLD16(Bhb + boff[p] + kb * 2, (char*)sBh + bdst[p]);
      GLD16(Blb + boff[p] + kb * 2, (char*)sBl + bdst[p]);
    }
    __syncthreads();

    bf16x8 ah[4], al[4];
#pragma unroll
    for (int mt = 0; mt < 4; mt++) {
      int row = Am0 + mt * 16 + l15, r7 = row & 7;
      const float* f0 = (const float*)((const char*)sA + row * 128 + (((2 * l4) ^ r7) * 16));
      const float* f1 = (const float*)((const char*)sA + row * 128 + (((2 * l4 + 1) ^ r7) * 16));
#pragma unroll
      for (int j = 0; j < 4; j++) {
        bf16 h, l;
        split2(f0[j], h, l);
        ah[mt][j] = h; al[mt][j] = l;
        split2(f1[j], h, l);
        ah[mt][4 + j] = h; al[mt][4 + j] = l;
      }
    }
#pragma unroll
    for (int nt = 0; nt < 4; nt++) {
      int row = Bn0 + nt * 16 + l15, r3 = row & 3;
      bf16x8 bh = *(const bf16x8*)((const char*)sBh + row * 64 + ((l4 ^ r3) * 16));
      bf16x8 bl = *(const bf16x8*)((const char*)sBl + row * 64 + ((l4 ^ r3) * 16));
#pragma unroll
      for (int mt = 0; mt < 4; mt++) {
        acc[mt][nt] = MFMA16(ah[mt], bh, acc[mt][nt]);
        acc[mt][nt] = MFMA16(ah[mt], bl, acc[mt][nt]);
        acc[mt][nt] = MFMA16(al[mt], bh, acc[mt][nt]);
      }
    }
  }

  const float scale = (which == 0) ? 0.125f : (which == 1) ? 1.44269504f : 1.0f;
#pragma unroll
  for (int mt = 0; mt < 4; mt++) {
#pragma unroll
    for (int nt = 0; nt < 4; nt++) {
      int m_base = m0 + Am0 + mt * 16 + l4 * 4;  // 4 consecutive rows (s)
      int n = n0 + Bn0 + nt * 16 + l15;          // h*64+d
      int h = (n >> 6) & 7, d = n & 63;
      if (which == 2) {
        // slot-permuted packed V^T store: keys 16t+4q+r -> column 8q+4t+r
        int kbase = m_base & 2047, b = m_base >> 11;
        int a32 = kbase & ~31, v = (kbase >> 2) & 7;
        int sbase = a32 + 8 * (v & 3) + 4 * (v >> 2);
        bf16x4 pv;
#pragma unroll
        for (int r = 0; r < 4; r++) pv[r] = (bf16)acc[mt][nt][r];
        *(bf16x4*)&Vt[((size_t)(b * 8 + h) * 64 + d) * 2048 + sbase] = pv;
      } else {
#pragma unroll
        for (int r = 0; r < 4; r++) {
          int m = m_base + r;
          int b = m >> 11, s = m & 2047;
          float v = acc[mt][nt][r] * scale;
          size_t o = ((size_t)(b * 8 + h) * 2048 + s) * 64 + d;
          if (which == 0) {
            bf16 hi, lo;
            split2(v, hi, lo);
            Q_hi[o] = hi; Q_lo[o] = lo;
          } else {
            K[o] = (bf16)v;  // single bf16 K
          }
        }
      }
    }
  }
}

// ---------------------------------------------------------------------------
// Flash attention: grid 1024 (XCD-swizzled), block 256 = 4 waves.
// Block: 64 q x 128-key tile; wave w owns keys [32w,32w+32).
// K (single bf16) + V staged via global_load_lds (LDS 33 KB).
// S^T = K Q^T (2-term: kh*qh + kh*ql); p = exp2(s - 24); PV consumes S^T
// C-layout directly as A (V columns pre-permuted). Two-phase epilogue reduce.
// ---------------------------------------------------------------------------
__global__ __launch_bounds__(256, 3) void k_flash(
    const bf16* __restrict__ Q_hi, const bf16* __restrict__ Q_lo,
    const bf16* __restrict__ K, const bf16* __restrict__ Vt,
    bf16* __restrict__ O_hi, bf16* __restrict__ O_lo) {
  const int P = blockIdx.x;
  const int hi4 = P >> 8, rem = P & 255;
  const int qt = rem >> 3;
  const int bh = hi4 * 8 + (rem & 7);
  const int b = bh >> 3, h = bh & 7;
  const int tid = threadIdx.x, wave = tid >> 6, lane = tid & 63;
  const int l15 = lane & 15, l4 = lane >> 4;
  const int q0 = qt * 64;

  __shared__ char smem[33792];  // sK 16KB @0 | sV 16KB @16384 | lbuf 1KB @32768
  bf16* sK = (bf16*)smem;
  bf16* sV = (bf16*)(smem + 16384);
  float* lbuf = (float*)(smem + 32768);

  // Q fragments (B operand): lane holds Q[q=l15][dh=l4*8+j]
  bf16x8 qh[4][2], ql[4][2];
#pragma unroll
  for (int nt = 0; nt < 4; nt++) {
    const bf16* ph = Q_hi + ((size_t)bh * 2048 + q0 + nt * 16 + l15) * 64 + l4 * 8;
    const bf16* pl = Q_lo + ((size_t)bh * 2048 + q0 + nt * 16 + l15) * 64 + l4 * 8;
    qh[nt][0] = *(const bf16x8*)ph;
    qh[nt][1] = *(const bf16x8*)(ph + 32);
    ql[nt][0] = *(const bf16x8*)pl;
    ql[nt][1] = *(const bf16x8*)(pl + 32);
  }

  const uint8_t* Kb = (const uint8_t*)K + (size_t)bh * 2048 * 128;
  const uint8_t* Vb = (const uint8_t*)Vt + (size_t)bh * 64 * 4096;
  int koff[4], voff[4], dst[4];
#pragma unroll
  for (int p = 0; p < 4; p++) {
    int slot = p * 256 + tid;
    {
      int row = slot >> 3, phys = slot & 7, lg = phys ^ (row & 7);
      koff[p] = row * 128 + lg * 16;
    }
    {
      int row = slot >> 4, phys = slot & 15, lg = phys ^ (row & 15);
      voff[p] = row * 4096 + lg * 16;
    }
    dst[p] = slot * 16;
  }

  float lp[4] = {0.f, 0.f, 0.f, 0.f};  // l partial per q-tile (q = nt*16+l15)
  floatx4 oacc[4][4];
#pragma unroll
  for (int i = 0; i < 4; i++)
#pragma unroll
    for (int j = 0; j < 4; j++) oacc[i][j] = {0.f, 0.f, 0.f, 0.f};

  for (int j0 = 0; j0 < 2048; j0 += 128) {
    __syncthreads();
#pragma unroll
    for (int p = 0; p < 4; p++) {
      GLD16(Kb + (size_t)j0 * 128 + koff[p], (char*)sK + dst[p]);
      GLD16(Vb + (size_t)j0 * 2 + voff[p], (char*)sV + dst[p]);
    }
    __syncthreads();

    // S^T = K Q^T - 24: sc[kt][nt] C-tile: row=key(16), col=q (l15)
    floatx4 sc[2][4];
#pragma unroll
    for (int kt = 0; kt < 2; kt++)
#pragma unroll
      for (int nt = 0; nt < 4; nt++)
        sc[kt][nt] = {-24.f, -24.f, -24.f, -24.f};
#pragma unroll
    for (int kt = 0; kt < 2; kt++) {
      int row = wave * 32 + kt * 16 + l15;
      int r7 = row & 7;
#pragma unroll
      for (int ks = 0; ks < 2; ks++) {
        bf16x8 kh = *(const bf16x8*)((const char*)sK +
                                     (row * 128 + (((ks * 4 + l4) ^ r7) * 16)));
#pragma unroll
        for (int nt = 0; nt < 4; nt++) {
          sc[kt][nt] = MFMA16(kh, qh[nt][ks], sc[kt][nt]);
          sc[kt][nt] = MFMA16(kh, ql[nt][ks], sc[kt][nt]);
        }
      }
    }

    // p = exp2(s); pf[nt] directly the PV A-operand (slot = quad*8 + 4*kt + r)
    bf16x8 pf[4];
#pragma unroll
    for (int nt = 0; nt < 4; nt++) {
#pragma unroll
      for (int r = 0; r < 4; r++) {
        float p0 = __builtin_amdgcn_exp2f(sc[0][nt][r]);
        float p1 = __builtin_amdgcn_exp2f(sc[1][nt][r]);
        lp[nt] += p0 + p1;
        pf[nt][r] = (bf16)p0;
        pf[nt][4 + r] = (bf16)p1;
      }
    }

    // O += P V over this wave's 32 slots
#pragma unroll
    for (int nt = 0; nt < 4; nt++) {  // dh tile
      int row = nt * 16 + l15;
      bf16x8 bv = *(const bf16x8*)((const char*)sV +
                                   (row * 256 + (((wave * 4 + l4) ^ l15) * 16)));
#pragma unroll
      for (int mq = 0; mq < 4; mq++)
        oacc[mq][nt] = MFMA16(pf[mq], bv, oacc[mq][nt]);
    }
  }

  // ---- epilogue: l reduce + two-phase cross-wave O reduction (24KB alias) ----
#pragma unroll
  for (int nt = 0; nt < 4; nt++) {
    lp[nt] += __shfl_xor(lp[nt], 16, 64);
    lp[nt] += __shfl_xor(lp[nt], 32, 64);
  }
  __syncthreads();  // everyone done with sK/sV
  if (l4 == 0) {
#pragma unroll
    for (int nt = 0; nt < 4; nt++) lbuf[wave * 64 + nt * 16 + l15] = lp[nt];
  }
  floatx4* red = (floatx4*)smem;  // 3 waves x 8 x 64 = 1536 floatx4 = 24KB
#pragma unroll
  for (int phase = 0; phase < 2; phase++) {
    if (wave >= 1) {
#pragma unroll
      for (int i = 0; i < 8; i++) {
        int mq = phase * 2 + (i >> 2);
        red[(wave - 1) * 512 + i * 64 + lane] = oacc[mq][i & 3];
      }
    }
    __syncthreads();
    if (wave == 0) {
#pragma unroll
      for (int i = 0; i < 8; i++) {
        int mq = phase * 2 + (i >> 2);
        oacc[mq][i & 3] += red[i * 64 + lane] + red[512 + i * 64 + lane] +
                           red[1024 + i * 64 + lane];
      }
    }
    __syncthreads();
  }
  if (wave == 0) {
    float lt[4];
#pragma unroll
    for (int nt = 0; nt < 4; nt++)
      lt[nt] = lbuf[nt * 16 + l15] + lbuf[64 + nt * 16 + l15] +
               lbuf[128 + nt * 16 + l15] + lbuf[192 + nt * 16 + l15];
    float rl[4][4];
#pragma unroll
    for (int mq = 0; mq < 4; mq++)
#pragma unroll
      for (int r = 0; r < 4; r++)
        rl[mq][r] = 1.0f / __shfl(lt[mq], (lane & 48) | (l4 * 4 + r), 64);
#pragma unroll
    for (int mq = 0; mq < 4; mq++) {
#pragma unroll
      for (int nt = 0; nt < 4; nt++) {
#pragma unroll
        for (int r = 0; r < 4; r++) {
          float v = oacc[mq][nt][r] * rl[mq][r];
          int gs = q0 + mq * 16 + l4 * 4 + r;
          int gd = h * 64 + nt * 16 + l15;
          size_t o = ((size_t)b * 2048 + gs) * 512 + gd;
          bf16 hi, lo;
          split2(v, hi, lo);
          O_hi[o] = hi;
          O_lo[o] = lo;
        }
      }
    }
  }
}

// ---------------------------------------------------------------------------
// Output projection, 128x128 tile, BK=32, global_load_lds. grid 256 (swizzled).
// ---------------------------------------------------------------------------
__global__ __launch_bounds__(256) void k_proj_out(
    const bf16* __restrict__ O_hi, const bf16* __restrict__ O_lo,
    const bf16* __restrict__ wt_hi, const bf16* __restrict__ wt_lo,
    float* __restrict__ out) {
  const int P = blockIdx.x;
  const int c = P >> 5, within = P & 31;
  const int n_idx = within >> 3, i8 = within & 7;
  const int g = (c << 3) | i8;
  const int m0 = g * 128, n0 = n_idx * 128;

  const uint8_t* Ahb = (const uint8_t*)O_hi;
  const uint8_t* Alb = (const uint8_t*)O_lo;
  const uint8_t* Bhb = (const uint8_t*)(wt_hi + (size_t)3 * 262144);
  const uint8_t* Blb = (const uint8_t*)(wt_lo + (size_t)3 * 262144);
  const int tid = threadIdx.x, wave = tid >> 6, lane = tid & 63;
  const int l15 = lane & 15, l4 = lane >> 4;
  const int Am0 = (wave & 1) * 64, Bn0 = (wave >> 1) * 64;

  __shared__ bf16 sAh[128 * 32], sAl[128 * 32];
  __shared__ bf16 sBh[128 * 32], sBl[128 * 32];

  int aoff[2], boff[2], dst[2];
#pragma unroll
  for (int p = 0; p < 2; p++) {
    int slot = p * 256 + tid;
    int row = slot >> 2, phys = slot & 3, lg = phys ^ (row & 3);
    aoff[p] = (m0 + row) * 1024 + lg * 16;
    boff[p] = (n0 + row) * 1024 + lg * 16;
    dst[p] = slot * 16;
  }

  floatx4 acc[4][4];
#pragma unroll
  for (int i = 0; i < 4; i++)
#pragma unroll
    for (int j = 0; j < 4; j++) acc[i][j] = {0.f, 0.f, 0.f, 0.f};

  for (int kb = 0; kb < 512; kb += 32) {
    __syncthreads();
#pragma unroll
    for (int p = 0; p < 2; p++) {
      GLD16(Ahb + aoff[p] + kb * 2, (char*)sAh + dst[p]);
      GLD16(Alb + aoff[p] + kb * 2, (char*)sAl + dst[p]);
      GLD16(Bhb + boff[p] + kb * 2, (char*)sBh + dst[p]);
      GLD16(Blb + boff[p] + kb * 2, (char*)sBl + dst[p]);
    }
    __syncthreads();

    bf16x8 ah[4], al[4];
#pragma unroll
    for (int mt = 0; mt < 4; mt++) {
      int row = Am0 + mt * 16 + l15, r3 = row & 3;
      ah[mt] = *(const bf16x8*)((const char*)sAh + row * 64 + ((l4 ^ r3) * 16));
      al[mt] = *(const bf16x8*)((const char*)sAl + row * 64 + ((l4 ^ r3) * 16));
    }
#pragma unroll
    for (int nt = 0; nt < 4; nt++) {
      int row = Bn0 + nt * 16 + l15, r3 = row & 3;
      bf16x8 bh = *(const bf16x8*)((const char*)sBh + row * 64 + ((l4 ^ r3) * 16));
      bf16x8 bl = *(const bf16x8*)((const char*)sBl + row * 64 + ((l4 ^ r3) * 16));
#pragma unroll
      for (int mt = 0; mt < 4; mt++) {
        acc[mt][nt] = MFMA16(ah[mt], bh, acc[mt][nt]);
        acc[mt][nt] = MFMA16(ah[mt], bl, acc[mt][nt]);
        acc[mt][nt] = MFMA16(al[mt], bh, acc[mt][nt]);
      }
    }
  }
#pragma unroll
  for (int mt = 0; mt < 4; mt++) {
#pragma unroll
    for (int nt = 0; nt < 4; nt++) {
#pragma unroll
      for (int r = 0; r < 4; r++) {
        int m = m0 + Am0 + mt * 16 + l4 * 4 + r;
        int n = n0 + Bn0 + nt * 16 + l15;
        out[(size_t)m * 512 + n] = acc[mt][nt][r];
      }
    }
  }
}

// ---------------------------------------------------------------------------
extern "C" void kernel_launch(void* const* d_in, const int* in_sizes, int n_in,
                              void* d_out, int out_size, void* d_ws, size_t ws_size,
                              hipStream_t stream) {
  (void)in_sizes; (void)n_in; (void)out_size; (void)ws_size;
  const float* Xq = (const float*)d_in[0];
  const float* Xk = (const float*)d_in[1];
  const float* Xv = (const float*)d_in[2];
  const float* Wq = (const float*)d_in[3];
  const float* Wk = (const float*)d_in[4];
  const float* Wv = (const float*)d_in[5];
  const float* Wo = (const float*)d_in[6];
  float* out = (float*)d_out;

  char* ws = (char*)d_ws;
  size_t off = 0;
  auto alloc = [&](size_t n) {
    void* p = ws + off;
    off += (n + 255) & ~(size_t)255;
    return p;
  };
  const size_t NW = 4 * 262144;
  const size_t NE = 4194304;  // 4*2048*512
  bf16* wt_hi = (bf16*)alloc(NW * 2);
  bf16* wt_lo = (bf16*)alloc(NW * 2);
  bf16* Qh = (bf16*)alloc(NE * 2);
  bf16* Ql = (bf16*)alloc(NE * 2);
  bf16* Kk = (bf16*)alloc(NE * 2);
  bf16* Vt = (bf16*)alloc(NE * 2);
  bf16* Oh = (bf16*)alloc(NE * 2);
  bf16* Ol = (bf16*)alloc(NE * 2);

  k_split_w<<<dim3(8, 8, 4), dim3(256), 0, stream>>>(Wq, Wk, Wv, Wo, wt_hi, wt_lo);
  k_proj_qkv<<<dim3(768), dim3(256), 0, stream>>>(Xq, Xk, Xv, wt_hi, wt_lo,
                                                  Qh, Ql, Kk, Vt);
  k_flash<<<dim3(1024), dim3(256), 0, stream>>>(Qh, Ql, Kk, Vt, Oh, Ol);
  k_proj_out<<<dim3(256), dim3(256), 0, stream>>>(Oh, Ol, wt_hi, wt_lo, out);
}

// Round 9
// 228.831 us; speedup vs baseline: 2.9698x; 1.4897x over previous
//
#include <hip/hip_runtime.h>
#include <hip/hip_bf16.h>
#include <cstdint>
#include <cstddef>

// MHA: B=4, S=2048, D=512, H=8, DH=64. fp32 in/out.
// R9: R8 structure (single-bf16 K, 2-term QK, key-split waves, permuted-V PV,
//     LDS 33 KB) with __launch_bounds__(256,2): unified reg cap 256 >= ~188
//     natural footprint -> NO spills (R7's cap 64 and R8's cap 170 both
//     spilled; unified VGPR+AGPR budget is 512/waves-per-EU).

typedef __bf16 bf16;
typedef __attribute__((ext_vector_type(8))) __bf16 bf16x8;
typedef __attribute__((ext_vector_type(4))) __bf16 bf16x4;
typedef __attribute__((ext_vector_type(4))) float floatx4;

#define MFMA16(a, b, c) __builtin_amdgcn_mfma_f32_16x16x32_bf16(a, b, c, 0, 0, 0)

#define GLD16(gp, lp)                                              \
  __builtin_amdgcn_global_load_lds(                                \
      (const __attribute__((address_space(1))) unsigned int*)(gp), \
      (__attribute__((address_space(3))) unsigned int*)(lp), 16, 0, 0)

__device__ __forceinline__ void split2(float x, bf16& hi, bf16& lo) {
  hi = (bf16)x;
  lo = (bf16)(x - (float)hi);
}

// ---------------------------------------------------------------------------
// Split + transpose the 4 weight matrices: wt[w][n][k] = W_w[k][n] as hi/lo bf16
// ---------------------------------------------------------------------------
__global__ __launch_bounds__(256) void k_split_w(
    const float* __restrict__ Wq, const float* __restrict__ Wk,
    const float* __restrict__ Wv, const float* __restrict__ Wo,
    bf16* __restrict__ wt_hi, bf16* __restrict__ wt_lo) {
  __shared__ float tile[64][65];
  const int w = blockIdx.z;
  const float* W = (w == 0) ? Wq : (w == 1) ? Wk : (w == 2) ? Wv : Wo;
  const int kb = blockIdx.y * 64, nb = blockIdx.x * 64;
  const int tid = threadIdx.x;
  const int col = tid & 63, rbase = tid >> 6;
#pragma unroll
  for (int i = 0; i < 16; i++) {
    int row = rbase + i * 4;
    tile[row][col] = W[(size_t)(kb + row) * 512 + nb + col];
  }
  __syncthreads();
#pragma unroll
  for (int i = 0; i < 16; i++) {
    int nrow = rbase + i * 4;
    float v = tile[col][nrow];
    bf16 hi, lo;
    split2(v, hi, lo);
    size_t o = (size_t)w * 262144 + (size_t)(nb + nrow) * 512 + (kb + col);
    wt_hi[o] = hi;
    wt_lo[o] = lo;
  }
}

// ---------------------------------------------------------------------------
// QKV projection, 128x128 C-tile, BK=32, global_load_lds staging.
// grid 768 (1-D, XCD-swizzled), block 256.
// Q split hi/lo, scaled 1/8. K SINGLE bf16, scaled log2(e). V single bf16,
// transposed with slot-permuted columns (key 16t+4q+r -> column 8q+4t+r per
// 32-group) so flash PV consumes S^T C-layout registers directly as A.
// ---------------------------------------------------------------------------
__global__ __launch_bounds__(256) void k_proj_qkv(
    const float* __restrict__ Xq, const float* __restrict__ Xk,
    const float* __restrict__ Xv,
    const bf16* __restrict__ wt_hi, const bf16* __restrict__ wt_lo,
    bf16* __restrict__ Q_hi, bf16* __restrict__ Q_lo,
    bf16* __restrict__ K, bf16* __restrict__ Vt) {
  const int P = blockIdx.x;
  const int c_all = P >> 5, within = P & 31;
  const int n_idx = within >> 3, i8 = within & 7;
  const int which = c_all >> 3;
  const int g = ((c_all & 7) << 3) | i8;  // m-group 0..63
  const int m0 = g * 128, n0 = n_idx * 128;

  const float* X = (which == 0) ? Xq : (which == 1) ? Xk : Xv;
  const uint8_t* Bhb = (const uint8_t*)(wt_hi + (size_t)which * 262144);
  const uint8_t* Blb = (const uint8_t*)(wt_lo + (size_t)which * 262144);
  const uint8_t* Xb = (const uint8_t*)X;
  const int tid = threadIdx.x, wave = tid >> 6, lane = tid & 63;
  const int l15 = lane & 15, l4 = lane >> 4;
  const int Am0 = (wave & 1) * 64, Bn0 = (wave >> 1) * 64;

  __shared__ float sA[128 * 32];                 // 16 KB, XOR-swizzled 16B blocks
  __shared__ bf16 sBh[128 * 32], sBl[128 * 32];  // 8 KB each

  int aoff[4], adst[4];
#pragma unroll
  for (int p = 0; p < 4; p++) {
    int slot = p * 256 + tid;
    int row = slot >> 3, phys = slot & 7, lg = phys ^ (row & 7);
    aoff[p] = (m0 + row) * 2048 + lg * 16;
    adst[p] = slot * 16;
  }
  int boff[2], bdst[2];
#pragma unroll
  for (int p = 0; p < 2; p++) {
    int slot = p * 256 + tid;
    int row = slot >> 2, phys = slot & 3, lg = phys ^ (row & 3);
    boff[p] = (n0 + row) * 1024 + lg * 16;
    bdst[p] = slot * 16;
  }

  floatx4 acc[4][4];
#pragma unroll
  for (int i = 0; i < 4; i++)
#pragma unroll
    for (int j = 0; j < 4; j++) acc[i][j] = {0.f, 0.f, 0.f, 0.f};

  for (int kb = 0; kb < 512; kb += 32) {
    __syncthreads();
#pragma unroll
    for (int p = 0; p < 4; p++) GLD16(Xb + aoff[p] + kb * 4, (char*)sA + adst[p]);
#pragma unroll
    for (int p = 0; p < 2; p++) {
      GLD16(Bhb + boff[p] + kb * 2, (char*)sBh + bdst[p]);
      GLD16(Blb + boff[p] + kb * 2, (char*)sBl + bdst[p]);
    }
    __syncthreads();

    bf16x8 ah[4], al[4];
#pragma unroll
    for (int mt = 0; mt < 4; mt++) {
      int row = Am0 + mt * 16 + l15, r7 = row & 7;
      const float* f0 = (const float*)((const char*)sA + row * 128 + (((2 * l4) ^ r7) * 16));
      const float* f1 = (const float*)((const char*)sA + row * 128 + (((2 * l4 + 1) ^ r7) * 16));
#pragma unroll
      for (int j = 0; j < 4; j++) {
        bf16 h, l;
        split2(f0[j], h, l);
        ah[mt][j] = h; al[mt][j] = l;
        split2(f1[j], h, l);
        ah[mt][4 + j] = h; al[mt][4 + j] = l;
      }
    }
#pragma unroll
    for (int nt = 0; nt < 4; nt++) {
      int row = Bn0 + nt * 16 + l15, r3 = row & 3;
      bf16x8 bh = *(const bf16x8*)((const char*)sBh + row * 64 + ((l4 ^ r3) * 16));
      bf16x8 bl = *(const bf16x8*)((const char*)sBl + row * 64 + ((l4 ^ r3) * 16));
#pragma unroll
      for (int mt = 0; mt < 4; mt++) {
        acc[mt][nt] = MFMA16(ah[mt], bh, acc[mt][nt]);
        acc[mt][nt] = MFMA16(ah[mt], bl, acc[mt][nt]);
        acc[mt][nt] = MFMA16(al[mt], bh, acc[mt][nt]);
      }
    }
  }

  const float scale = (which == 0) ? 0.125f : (which == 1) ? 1.44269504f : 1.0f;
#pragma unroll
  for (int mt = 0; mt < 4; mt++) {
#pragma unroll
    for (int nt = 0; nt < 4; nt++) {
      int m_base = m0 + Am0 + mt * 16 + l4 * 4;  // 4 consecutive rows (s)
      int n = n0 + Bn0 + nt * 16 + l15;          // h*64+d
      int h = (n >> 6) & 7, d = n & 63;
      if (which == 2) {
        // slot-permuted packed V^T store: keys 16t+4q+r -> column 8q+4t+r
        int kbase = m_base & 2047, b = m_base >> 11;
        int a32 = kbase & ~31, v = (kbase >> 2) & 7;
        int sbase = a32 + 8 * (v & 3) + 4 * (v >> 2);
        bf16x4 pv;
#pragma unroll
        for (int r = 0; r < 4; r++) pv[r] = (bf16)acc[mt][nt][r];
        *(bf16x4*)&Vt[((size_t)(b * 8 + h) * 64 + d) * 2048 + sbase] = pv;
      } else {
#pragma unroll
        for (int r = 0; r < 4; r++) {
          int m = m_base + r;
          int b = m >> 11, s = m & 2047;
          float v = acc[mt][nt][r] * scale;
          size_t o = ((size_t)(b * 8 + h) * 2048 + s) * 64 + d;
          if (which == 0) {
            bf16 hi, lo;
            split2(v, hi, lo);
            Q_hi[o] = hi; Q_lo[o] = lo;
          } else {
            K[o] = (bf16)v;  // single bf16 K
          }
        }
      }
    }
  }
}

// ---------------------------------------------------------------------------
// Flash attention: grid 1024 (XCD-swizzled), block 256 = 4 waves.
// Block: 64 q x 128-key tile; wave w owns keys [32w,32w+32).
// K (single bf16) + V staged via global_load_lds (LDS 33 KB).
// S^T = K Q^T (2-term: kh*qh + kh*ql); p = exp2(s - 24); PV consumes S^T
// C-layout directly as A (V columns pre-permuted). Two-phase epilogue reduce.
// launch_bounds (256,2): unified reg cap 256 >= ~188 demand -> no spills.
// ---------------------------------------------------------------------------
__global__ __launch_bounds__(256, 2) void k_flash(
    const bf16* __restrict__ Q_hi, const bf16* __restrict__ Q_lo,
    const bf16* __restrict__ K, const bf16* __restrict__ Vt,
    bf16* __restrict__ O_hi, bf16* __restrict__ O_lo) {
  const int P = blockIdx.x;
  const int hi4 = P >> 8, rem = P & 255;
  const int qt = rem >> 3;
  const int bh = hi4 * 8 + (rem & 7);
  const int b = bh >> 3, h = bh & 7;
  const int tid = threadIdx.x, wave = tid >> 6, lane = tid & 63;
  const int l15 = lane & 15, l4 = lane >> 4;
  const int q0 = qt * 64;

  __shared__ char smem[33792];  // sK 16KB @0 | sV 16KB @16384 | lbuf 1KB @32768
  bf16* sK = (bf16*)smem;
  bf16* sV = (bf16*)(smem + 16384);
  float* lbuf = (float*)(smem + 32768);

  // Q fragments (B operand): lane holds Q[q=l15][dh=l4*8+j]
  bf16x8 qh[4][2], ql[4][2];
#pragma unroll
  for (int nt = 0; nt < 4; nt++) {
    const bf16* ph = Q_hi + ((size_t)bh * 2048 + q0 + nt * 16 + l15) * 64 + l4 * 8;
    const bf16* pl = Q_lo + ((size_t)bh * 2048 + q0 + nt * 16 + l15) * 64 + l4 * 8;
    qh[nt][0] = *(const bf16x8*)ph;
    qh[nt][1] = *(const bf16x8*)(ph + 32);
    ql[nt][0] = *(const bf16x8*)pl;
    ql[nt][1] = *(const bf16x8*)(pl + 32);
  }

  const uint8_t* Kb = (const uint8_t*)K + (size_t)bh * 2048 * 128;
  const uint8_t* Vb = (const uint8_t*)Vt + (size_t)bh * 64 * 4096;
  int koff[4], voff[4], dst[4];
#pragma unroll
  for (int p = 0; p < 4; p++) {
    int slot = p * 256 + tid;
    {
      int row = slot >> 3, phys = slot & 7, lg = phys ^ (row & 7);
      koff[p] = row * 128 + lg * 16;
    }
    {
      int row = slot >> 4, phys = slot & 15, lg = phys ^ (row & 15);
      voff[p] = row * 4096 + lg * 16;
    }
    dst[p] = slot * 16;
  }

  float lp[4] = {0.f, 0.f, 0.f, 0.f};  // l partial per q-tile (q = nt*16+l15)
  floatx4 oacc[4][4];
#pragma unroll
  for (int i = 0; i < 4; i++)
#pragma unroll
    for (int j = 0; j < 4; j++) oacc[i][j] = {0.f, 0.f, 0.f, 0.f};

  for (int j0 = 0; j0 < 2048; j0 += 128) {
    __syncthreads();
#pragma unroll
    for (int p = 0; p < 4; p++) {
      GLD16(Kb + (size_t)j0 * 128 + koff[p], (char*)sK + dst[p]);
      GLD16(Vb + (size_t)j0 * 2 + voff[p], (char*)sV + dst[p]);
    }
    __syncthreads();

    // S^T = K Q^T - 24: sc[kt][nt] C-tile: row=key(16), col=q (l15)
    floatx4 sc[2][4];
#pragma unroll
    for (int kt = 0; kt < 2; kt++)
#pragma unroll
      for (int nt = 0; nt < 4; nt++)
        sc[kt][nt] = {-24.f, -24.f, -24.f, -24.f};
#pragma unroll
    for (int kt = 0; kt < 2; kt++) {
      int row = wave * 32 + kt * 16 + l15;
      int r7 = row & 7;
#pragma unroll
      for (int ks = 0; ks < 2; ks++) {
        bf16x8 kh = *(const bf16x8*)((const char*)sK +
                                     (row * 128 + (((ks * 4 + l4) ^ r7) * 16)));
#pragma unroll
        for (int nt = 0; nt < 4; nt++) {
          sc[kt][nt] = MFMA16(kh, qh[nt][ks], sc[kt][nt]);
          sc[kt][nt] = MFMA16(kh, ql[nt][ks], sc[kt][nt]);
        }
      }
    }

    // p = exp2(s); pf[nt] directly the PV A-operand (slot = quad*8 + 4*kt + r)
    bf16x8 pf[4];
#pragma unroll
    for (int nt = 0; nt < 4; nt++) {
#pragma unroll
      for (int r = 0; r < 4; r++) {
        float p0 = __builtin_amdgcn_exp2f(sc[0][nt][r]);
        float p1 = __builtin_amdgcn_exp2f(sc[1][nt][r]);
        lp[nt] += p0 + p1;
        pf[nt][r] = (bf16)p0;
        pf[nt][4 + r] = (bf16)p1;
      }
    }

    // O += P V over this wave's 32 slots
#pragma unroll
    for (int nt = 0; nt < 4; nt++) {  // dh tile
      int row = nt * 16 + l15;
      bf16x8 bv = *(const bf16x8*)((const char*)sV +
                                   (row * 256 + (((wave * 4 + l4) ^ l15) * 16)));
#pragma unroll
      for (int mq = 0; mq < 4; mq++)
        oacc[mq][nt] = MFMA16(pf[mq], bv, oacc[mq][nt]);
    }
  }

  // ---- epilogue: l reduce + two-phase cross-wave O reduction (24KB alias) ----
#pragma unroll
  for (int nt = 0; nt < 4; nt++) {
    lp[nt] += __shfl_xor(lp[nt], 16, 64);
    lp[nt] += __shfl_xor(lp[nt], 32, 64);
  }
  __syncthreads();  // everyone done with sK/sV
  if (l4 == 0) {
#pragma unroll
    for (int nt = 0; nt < 4; nt++) lbuf[wave * 64 + nt * 16 + l15] = lp[nt];
  }
  floatx4* red = (floatx4*)smem;  // 3 waves x 8 x 64 = 1536 floatx4 = 24KB
#pragma unroll
  for (int phase = 0; phase < 2; phase++) {
    if (wave >= 1) {
#pragma unroll
      for (int i = 0; i < 8; i++) {
        int mq = phase * 2 + (i >> 2);
        red[(wave - 1) * 512 + i * 64 + lane] = oacc[mq][i & 3];
      }
    }
    __syncthreads();
    if (wave == 0) {
#pragma unroll
      for (int i = 0; i < 8; i++) {
        int mq = phase * 2 + (i >> 2);
        oacc[mq][i & 3] += red[i * 64 + lane] + red[512 + i * 64 + lane] +
                           red[1024 + i * 64 + lane];
      }
    }
    __syncthreads();
  }
  if (wave == 0) {
    float lt[4];
#pragma unroll
    for (int nt = 0; nt < 4; nt++)
      lt[nt] = lbuf[nt * 16 + l15] + lbuf[64 + nt * 16 + l15] +
               lbuf[128 + nt * 16 + l15] + lbuf[192 + nt * 16 + l15];
    float rl[4][4];
#pragma unroll
    for (int mq = 0; mq < 4; mq++)
#pragma unroll
      for (int r = 0; r < 4; r++)
        rl[mq][r] = 1.0f / __shfl(lt[mq], (lane & 48) | (l4 * 4 + r), 64);
#pragma unroll
    for (int mq = 0; mq < 4; mq++) {
#pragma unroll
      for (int nt = 0; nt < 4; nt++) {
#pragma unroll
        for (int r = 0; r < 4; r++) {
          float v = oacc[mq][nt][r] * rl[mq][r];
          int gs = q0 + mq * 16 + l4 * 4 + r;
          int gd = h * 64 + nt * 16 + l15;
          size_t o = ((size_t)b * 2048 + gs) * 512 + gd;
          bf16 hi, lo;
          split2(v, hi, lo);
          O_hi[o] = hi;
          O_lo[o] = lo;
        }
      }
    }
  }
}

// ---------------------------------------------------------------------------
// Output projection, 128x128 tile, BK=32, global_load_lds. grid 256 (swizzled).
// ---------------------------------------------------------------------------
__global__ __launch_bounds__(256) void k_proj_out(
    const bf16* __restrict__ O_hi, const bf16* __restrict__ O_lo,
    const bf16* __restrict__ wt_hi, const bf16* __restrict__ wt_lo,
    float* __restrict__ out) {
  const int P = blockIdx.x;
  const int c = P >> 5, within = P & 31;
  const int n_idx = within >> 3, i8 = within & 7;
  const int g = (c << 3) | i8;
  const int m0 = g * 128, n0 = n_idx * 128;

  const uint8_t* Ahb = (const uint8_t*)O_hi;
  const uint8_t* Alb = (const uint8_t*)O_lo;
  const uint8_t* Bhb = (const uint8_t*)(wt_hi + (size_t)3 * 262144);
  const uint8_t* Blb = (const uint8_t*)(wt_lo + (size_t)3 * 262144);
  const int tid = threadIdx.x, wave = tid >> 6, lane = tid & 63;
  const int l15 = lane & 15, l4 = lane >> 4;
  const int Am0 = (wave & 1) * 64, Bn0 = (wave >> 1) * 64;

  __shared__ bf16 sAh[128 * 32], sAl[128 * 32];
  __shared__ bf16 sBh[128 * 32], sBl[128 * 32];

  int aoff[2], boff[2], dst[2];
#pragma unroll
  for (int p = 0; p < 2; p++) {
    int slot = p * 256 + tid;
    int row = slot >> 2, phys = slot & 3, lg = phys ^ (row & 3);
    aoff[p] = (m0 + row) * 1024 + lg * 16;
    boff[p] = (n0 + row) * 1024 + lg * 16;
    dst[p] = slot * 16;
  }

  floatx4 acc[4][4];
#pragma unroll
  for (int i = 0; i < 4; i++)
#pragma unroll
    for (int j = 0; j < 4; j++) acc[i][j] = {0.f, 0.f, 0.f, 0.f};

  for (int kb = 0; kb < 512; kb += 32) {
    __syncthreads();
#pragma unroll
    for (int p = 0; p < 2; p++) {
      GLD16(Ahb + aoff[p] + kb * 2, (char*)sAh + dst[p]);
      GLD16(Alb + aoff[p] + kb * 2, (char*)sAl + dst[p]);
      GLD16(Bhb + boff[p] + kb * 2, (char*)sBh + dst[p]);
      GLD16(Blb + boff[p] + kb * 2, (char*)sBl + dst[p]);
    }
    __syncthreads();

    bf16x8 ah[4], al[4];
#pragma unroll
    for (int mt = 0; mt < 4; mt++) {
      int row = Am0 + mt * 16 + l15, r3 = row & 3;
      ah[mt] = *(const bf16x8*)((const char*)sAh + row * 64 + ((l4 ^ r3) * 16));
      al[mt] = *(const bf16x8*)((const char*)sAl + row * 64 + ((l4 ^ r3) * 16));
    }
#pragma unroll
    for (int nt = 0; nt < 4; nt++) {
      int row = Bn0 + nt * 16 + l15, r3 = row & 3;
      bf16x8 bh = *(const bf16x8*)((const char*)sBh + row * 64 + ((l4 ^ r3) * 16));
      bf16x8 bl = *(const bf16x8*)((const char*)sBl + row * 64 + ((l4 ^ r3) * 16));
#pragma unroll
      for (int mt = 0; mt < 4; mt++) {
        acc[mt][nt] = MFMA16(ah[mt], bh, acc[mt][nt]);
        acc[mt][nt] = MFMA16(ah[mt], bl, acc[mt][nt]);
        acc[mt][nt] = MFMA16(al[mt], bh, acc[mt][nt]);
      }
    }
  }
#pragma unroll
  for (int mt = 0; mt < 4; mt++) {
#pragma unroll
    for (int nt = 0; nt < 4; nt++) {
#pragma unroll
      for (int r = 0; r < 4; r++) {
        int m = m0 + Am0 + mt * 16 + l4 * 4 + r;
        int n = n0 + Bn0 + nt * 16 + l15;
        out[(size_t)m * 512 + n] = acc[mt][nt][r];
      }
    }
  }
}

// ---------------------------------------------------------------------------
extern "C" void kernel_launch(void* const* d_in, const int* in_sizes, int n_in,
                              void* d_out, int out_size, void* d_ws, size_t ws_size,
                              hipStream_t stream) {
  (void)in_sizes; (void)n_in; (void)out_size; (void)ws_size;
  const float* Xq = (const float*)d_in[0];
  const float* Xk = (const float*)d_in[1];
  const float* Xv = (const float*)d_in[2];
  const float* Wq = (const float*)d_in[3];
  const float* Wk = (const float*)d_in[4];
  const float* Wv = (const float*)d_in[5];
  const float* Wo = (const float*)d_in[6];
  float* out = (float*)d_out;

  char* ws = (char*)d_ws;
  size_t off = 0;
  auto alloc = [&](size_t n) {
    void* p = ws + off;
    off += (n + 255) & ~(size_t)255;
    return p;
  };
  const size_t NW = 4 * 262144;
  const size_t NE = 4194304;  // 4*2048*512
  bf16* wt_hi = (bf16*)alloc(NW * 2);
  bf16* wt_lo = (bf16*)alloc(NW * 2);
  bf16* Qh = (bf16*)alloc(NE * 2);
  bf16* Ql = (bf16*)alloc(NE * 2);
  bf16* Kk = (bf16*)alloc(NE * 2);
  bf16* Vt = (bf16*)alloc(NE * 2);
  bf16* Oh = (bf16*)alloc(NE * 2);
  bf16* Ol = (bf16*)alloc(NE * 2);

  k_split_w<<<dim3(8, 8, 4), dim3(256), 0, stream>>>(Wq, Wk, Wv, Wo, wt_hi, wt_lo);
  k_proj_qkv<<<dim3(768), dim3(256), 0, stream>>>(Xq, Xk, Xv, wt_hi, wt_lo,
                                                  Qh, Ql, Kk, Vt);
  k_flash<<<dim3(1024), dim3(256), 0, stream>>>(Qh, Ql, Kk, Vt, Oh, Ol);
  k_proj_out<<<dim3(256), dim3(256), 0, stream>>>(Oh, Ol, wt_hi, wt_lo, out);
}